// Round 10
// baseline (72.328 us; speedup 1.0000x reference)
//
#include <hip/hip_runtime.h>
#include <hip/hip_bf16.h>

#define B_   8
#define LQ_  128
#define LK_  1024
#define H_   128
#define NITEMS (B_ * LQ_)            // 1024 work items = (b, l) rows

// exp(2*proj) in module BSS. tanh(q+k) = 1 - 2/(EQ*EK + 1).
__device__ float g_eq[B_ * LQ_ * H_];
__device__ float g_ek[B_ * LK_ * H_];
__device__ unsigned int g_wq;        // work-queue counter (reset by proj_kernel)

#define C2LOG2E 2.8853900817779268f  // 2/ln2

// Tiled projection (R8/R9-proven), epilogue writes exp(2*acc).
// Block 0 thread 0 also resets the fused kernel's work queue (proj always
// completes before fused_attn starts: same stream).
__global__ __launch_bounds__(256) void proj_kernel(const float* __restrict__ q,
                                                   const float* __restrict__ k,
                                                   const float* __restrict__ Wq,
                                                   const float* __restrict__ Wk) {
    if (blockIdx.x == 0 && threadIdx.x == 0) g_wq = 0u;
    __shared__ float Ws[H_ * H_];    // 64 KB
    __shared__ float Xs[32 * H_];    // 16 KB
    const int t = threadIdx.x;
    const int tile = blockIdx.x;
    const float* X; const float* W; float* Y; int r0;
    if (tile < 32) { X = q; W = Wq; Y = g_eq; r0 = tile * 32; }
    else           { X = k; W = Wk; Y = g_ek; r0 = (tile - 32) * 32; }

    #pragma unroll
    for (int u = 0; u < 16; ++u) {
        int idx = u * 256 + t;
        *(float4*)(Ws + idx * 4) = *(const float4*)(W + idx * 4);
    }
    #pragma unroll
    for (int u = 0; u < 4; ++u) {
        int idx = u * 256 + t;
        int r = idx >> 5, c = idx & 31;
        *(float4*)(Xs + r * H_ + c * 4) = *(const float4*)(X + (r0 + r) * H_ + c * 4);
    }
    __syncthreads();

    const int r4 = t >> 5;
    const int c4 = t & 31;
    float acc[4][4] = {};
    #pragma unroll 4
    for (int kk = 0; kk < H_; ++kk) {
        float4 w4 = *(const float4*)(Ws + kk * H_ + c4 * 4);
        #pragma unroll
        for (int i = 0; i < 4; ++i) {
            float x = Xs[(r4 * 4 + i) * H_ + kk];
            acc[i][0] = fmaf(x, w4.x, acc[i][0]);
            acc[i][1] = fmaf(x, w4.y, acc[i][1]);
            acc[i][2] = fmaf(x, w4.z, acc[i][2]);
            acc[i][3] = fmaf(x, w4.w, acc[i][3]);
        }
    }
    #pragma unroll
    for (int i = 0; i < 4; ++i) {
        float4 o;
        o.x = __builtin_amdgcn_exp2f(acc[i][0] * C2LOG2E);
        o.y = __builtin_amdgcn_exp2f(acc[i][1] * C2LOG2E);
        o.z = __builtin_amdgcn_exp2f(acc[i][2] * C2LOG2E);
        o.w = __builtin_amdgcn_exp2f(acc[i][3] * C2LOG2E);
        *(float4*)(Y + (r0 + r4 * 4 + i) * H_ + c4 * 4) = o;
    }
}

// Persistent-block fused attention. 512 blocks x 512 threads pull (b,l) items
// from a device queue (load-balanced across random valid_lens).
// Phase 1 (wave-centric, coalesced): wave handles 2 s-rows/iter; lane =
// (row-half, h4); one float4 load per lane = two contiguous rows per wave.
// Score = wsum - 2*sum_h w_h * rcp(EQ_h*EK_h + 1); 5 shfl_xor reduce.
// Phase 2: block softmax (shfl + LDS). Phase 3: float2 PV, 8-way s-split.
// Every item's math is block-independent; writes disjoint -> deterministic.
__global__ __launch_bounds__(512, 2) void fused_attn(const float* __restrict__ values,
                                                     const int* __restrict__ valid_lens,
                                                     const float* __restrict__ w_v,
                                                     float* __restrict__ out) {
    __shared__ float sc[LK_];        // 4 KB: scores -> weights for the row
    __shared__ float red[8];
    __shared__ float sred[8];
    __shared__ float part[8][H_];    // 4 KB: PV partials
    __shared__ unsigned wi_s;

    const int t = threadIdx.x;
    const int lane = t & 63, wv_id = t >> 6;   // 8 waves
    const int half = lane >> 5;                // s-row within pair
    const int h4 = lane & 31;                  // float4 index within row

    // invariant per-lane fragments
    const float4 w4 = *(const float4*)(w_v + h4 * 4);
    float wsum = w4.x + w4.y + w4.z + w4.w;
    #pragma unroll
    for (int m = 1; m < 32; m <<= 1) wsum += __shfl_xor(wsum, m, 64);

    const int c = t >> 6;            // PV s-chunk (== wv_id, wave-uniform)
    const int v2 = t & 63;           // PV float2 column

    for (;;) {
        if (t == 0) wi_s = atomicAdd(&g_wq, 1u);
        __syncthreads();
        const unsigned wi = wi_s;
        if (wi >= NITEMS) break;
        const int b = (int)(wi >> 7), l = (int)(wi & 127);
        int valid = valid_lens[b];
        valid = min(max(valid, 0), LK_);

        const float4 q4 = *(const float4*)(g_eq + (size_t)(b * LQ_ + l) * H_ + h4 * 4);

        // ---- Phase 1: scores, coalesced (2 contiguous rows per wave-iter) ----
        #pragma unroll 2
        for (int sp = wv_id; 2 * sp < valid; sp += 8) {
            const int s = 2 * sp + half;                 // s <= 1023 always
            const float4 e4 = *(const float4*)(g_ek + (size_t)(b * LK_ + s) * H_ + h4 * 4);
            float a;
            a = w4.x * __builtin_amdgcn_rcpf(fmaf(q4.x, e4.x, 1.0f));
            a = fmaf(w4.y, __builtin_amdgcn_rcpf(fmaf(q4.y, e4.y, 1.0f)), a);
            a = fmaf(w4.z, __builtin_amdgcn_rcpf(fmaf(q4.z, e4.z, 1.0f)), a);
            a = fmaf(w4.w, __builtin_amdgcn_rcpf(fmaf(q4.w, e4.w, 1.0f)), a);
            #pragma unroll
            for (int m = 1; m < 32; m <<= 1) a += __shfl_xor(a, m, 64);
            if (h4 == 0 && s < valid) sc[s] = fmaf(-2.0f, a, wsum);
        }
        __syncthreads();

        // ---- Phase 2: masked softmax (weights in sc, 1/sum in rinv) ----
        int n;
        float rinv;
        if (valid == 0) {            // ref: all -1e6 -> uniform
            n = LK_;
            for (int i = t; i < LK_; i += 512) sc[i] = 1.0f;
            rinv = 1.0f / 1024.0f;
            __syncthreads();
        } else {
            n = valid;
            float m = -3.0e38f;
            for (int i = t; i < n; i += 512) m = fmaxf(m, sc[i]);
            #pragma unroll
            for (int kk = 32; kk; kk >>= 1) m = fmaxf(m, __shfl_xor(m, kk, 64));
            if (lane == 0) red[wv_id] = m;
            __syncthreads();
            m = fmaxf(fmaxf(fmaxf(red[0], red[1]), fmaxf(red[2], red[3])),
                      fmaxf(fmaxf(red[4], red[5]), fmaxf(red[6], red[7])));
            float ps = 0.0f;
            for (int i = t; i < n; i += 512) {
                float e = __builtin_amdgcn_exp2f((sc[i] - m) * 1.44269504f);
                sc[i] = e;
                ps += e;
            }
            #pragma unroll
            for (int kk = 32; kk; kk >>= 1) ps += __shfl_xor(ps, kk, 64);
            if (lane == 0) sred[wv_id] = ps;
            __syncthreads();
            float s8 = ((sred[0] + sred[1]) + (sred[2] + sred[3]))
                     + ((sred[4] + sred[5]) + (sred[6] + sred[7]));
            rinv = 1.0f / s8;
        }

        // ---- Phase 3: PV, float2 loads, 8-way s-split ----
        const float* vb = values + (size_t)b * LK_ * H_ + 2 * v2;
        float ax = 0.0f, ay = 0.0f;
        #pragma unroll 4
        for (int s = c; s < n; s += 8) {
            float2 vv = *(const float2*)(vb + (size_t)s * H_);
            float w = sc[s];
            ax = fmaf(w, vv.x, ax);
            ay = fmaf(w, vv.y, ay);
        }
        *(float2*)(&part[c][2 * v2]) = make_float2(ax, ay);
        __syncthreads();
        if (t < H_) {
            float o = ((part[0][t] + part[1][t]) + (part[2][t] + part[3][t]))
                    + ((part[4][t] + part[5][t]) + (part[6][t] + part[7][t]));
            out[(b * LQ_ + l) * H_ + t] = o * rinv;
        }
        __syncthreads();             // protect sc/part/wi_s before next item
    }
}

extern "C" void kernel_launch(void* const* d_in, const int* in_sizes, int n_in,
                              void* d_out, int out_size, void* d_ws, size_t ws_size,
                              hipStream_t stream) {
    const float* queries    = (const float*)d_in[0];
    const float* keys       = (const float*)d_in[1];
    const float* values     = (const float*)d_in[2];
    const int*   valid_lens = (const int*)d_in[3];
    const float* W_q        = (const float*)d_in[4];
    const float* W_k        = (const float*)d_in[5];
    const float* w_v        = (const float*)d_in[6];
    float* out = (float*)d_out;
    (void)d_ws; (void)ws_size; (void)in_sizes; (void)n_in; (void)out_size;

    proj_kernel<<<288, 256, 0, stream>>>(queries, keys, W_q, W_k);
    fused_attn <<<512, 512, 0, stream>>>(values, valid_lens, w_v, out);
}